// Round 1
// baseline (2966.818 us; speedup 1.0000x reference)
//
#include <hip/hip_runtime.h>
#include <hip/hip_bf16.h>

static constexpr int F = 128;
static constexpr int H = 128;

// ---------------------------------------------------------------------------
// Kernel 0: detect whether edge_index is int64 (little-endian) or int32.
// Values are < 100000 < 2^17, so int64 layout has every odd 32-bit word == 0.
// ---------------------------------------------------------------------------
__global__ void detect_dtype(const unsigned* __restrict__ ei, int* __restrict__ flag) {
  if (blockIdx.x == 0 && threadIdx.x == 0) {
    int is64 = 1;
    for (int i = 0; i < 64; ++i) {
      if (ei[2 * i + 1] != 0u) { is64 = 0; break; }
    }
    *flag = is64;
  }
}

// ---------------------------------------------------------------------------
// Kernel 1: scatter-add x[src] into agg[dst] (agg lives in d_out), count deg.
// 32 threads per edge, float4 per thread.
// ---------------------------------------------------------------------------
__global__ __launch_bounds__(256) void scatter_mean(
    const float* __restrict__ x, const void* __restrict__ eiv,
    const int* __restrict__ flag, float* __restrict__ agg,
    float* __restrict__ deg, int E) {
  long long gid = (long long)blockIdx.x * blockDim.x + threadIdx.x;
  int e = (int)(gid >> 5);
  int ch = (int)(gid & 31);
  if (e >= E) return;
  int src, dst;
  if (*flag) {
    const long long* ei = (const long long*)eiv;
    src = (int)ei[e];
    dst = (int)ei[E + e];
  } else {
    const int* ei = (const int*)eiv;
    src = ei[e];
    dst = ei[E + e];
  }
  float4 v = *(const float4*)(x + (size_t)src * F + ch * 4);
  float* a = agg + (size_t)dst * H + ch * 4;
  atomicAdd(a + 0, v.x);
  atomicAdd(a + 1, v.y);
  atomicAdd(a + 2, v.z);
  atomicAdd(a + 3, v.w);
  if (ch == 0) atomicAdd(deg + dst, 1.0f);
}

// ---------------------------------------------------------------------------
// Kernel 2: fused  out = L2norm_row(relu-pre)  where pre = aggm@Wl + bl + x@Wr
//           then ReLU, store, and accumulate per-column sum / sumsq for BN.
// Block: 256 threads, 16 rows. agg is read from `out` and overwritten in place
// (same rows only). Threads: c = t&127 (output column), half = t>>7 (rows 0-7
// or 8-15). A-tile staged in LDS; As reads are wave-uniform (broadcast).
// ---------------------------------------------------------------------------
__global__ __launch_bounds__(256) void fused_gemm(
    const float* __restrict__ x, const float* __restrict__ Wl,
    const float* __restrict__ bl, const float* __restrict__ Wr,
    const float* __restrict__ deg, float* __restrict__ out,
    float* __restrict__ colsum, float* __restrict__ colsq) {
  __shared__ float As[16][256];
  __shared__ float invd[16];
  __shared__ float rp[4][8];
  __shared__ float rscale[16];
  __shared__ float cs[128], cs2[128];

  const int t = threadIdx.x;
  const int i0 = blockIdx.x * 16;

  if (t < 16) invd[t] = 1.0f / fmaxf(deg[i0 + t], 1.0f);
  __syncthreads();

  // Stage A-tile: As[r][0..127] = agg row (normalized by deg), As[r][128..255] = x row
  #pragma unroll
  for (int it = 0; it < 2; ++it) {
    int idx = (it * 256 + t) * 4;  // 0..2044
    int r = idx >> 7, c = idx & 127;
    float s = invd[r];
    float4 va = *(const float4*)(out + (size_t)(i0 + r) * H + c);
    As[r][c + 0] = va.x * s; As[r][c + 1] = va.y * s;
    As[r][c + 2] = va.z * s; As[r][c + 3] = va.w * s;
    float4 vx = *(const float4*)(x + (size_t)(i0 + r) * F + c);
    As[r][128 + c + 0] = vx.x; As[r][128 + c + 1] = vx.y;
    As[r][128 + c + 2] = vx.z; As[r][128 + c + 3] = vx.w;
  }
  __syncthreads();

  const int c = t & 127;
  const int half = t >> 7;
  float acc[8];
  #pragma unroll
  for (int r = 0; r < 8; ++r) acc[r] = 0.0f;

  #pragma unroll 4
  for (int k = 0; k < 128; ++k) {
    float w = Wl[k * H + c];
    #pragma unroll
    for (int r = 0; r < 8; ++r) acc[r] = fmaf(As[half * 8 + r][k], w, acc[r]);
  }
  #pragma unroll 4
  for (int k = 0; k < 128; ++k) {
    float w = Wr[k * H + c];
    #pragma unroll
    for (int r = 0; r < 8; ++r) acc[r] = fmaf(As[half * 8 + r][128 + k], w, acc[r]);
  }
  const float bias = bl[c];
  #pragma unroll
  for (int r = 0; r < 8; ++r) acc[r] += bias;

  // Row L2 norms: each row's 128 values live across 2 waves (same `half`).
  float sq[8];
  #pragma unroll
  for (int r = 0; r < 8; ++r) sq[r] = acc[r] * acc[r];
  #pragma unroll
  for (int off = 32; off > 0; off >>= 1) {
    #pragma unroll
    for (int r = 0; r < 8; ++r) sq[r] += __shfl_down(sq[r], off, 64);
  }
  const int wv = t >> 6;
  if ((t & 63) == 0) {
    #pragma unroll
    for (int r = 0; r < 8; ++r) rp[wv][r] = sq[r];
  }
  __syncthreads();
  if (t < 16) {
    int base = (t >> 3) * 2, rr = t & 7;
    float s = rp[base][rr] + rp[base + 1][rr];
    rscale[t] = 1.0f / fmaxf(sqrtf(s), 1e-12f);
  }
  __syncthreads();

  // normalize, ReLU, store (pre-BN), accumulate column stats
  float csum = 0.0f, csq = 0.0f;
  #pragma unroll
  for (int r = 0; r < 8; ++r) {
    float v = fmaxf(acc[r] * rscale[half * 8 + r], 0.0f);
    out[(size_t)(i0 + half * 8 + r) * H + c] = v;
    csum += v;
    csq += v * v;
  }
  if (half == 1) { cs[c] = csum; cs2[c] = csq; }
  __syncthreads();
  if (half == 0) {
    atomicAdd(&colsum[c], csum + cs[c]);
    atomicAdd(&colsq[c], csq + cs2[c]);
  }
}

// ---------------------------------------------------------------------------
// Kernel 3: finalize BN stats -> per-column scale/shift
// ---------------------------------------------------------------------------
__global__ void bn_stats(const float* __restrict__ colsum, const float* __restrict__ colsq,
                         const float* __restrict__ gamma, const float* __restrict__ beta,
                         float* __restrict__ scale, float* __restrict__ shift, int n) {
  int c = threadIdx.x;
  if (c < H) {
    float inv_n = 1.0f / (float)n;
    float mean = colsum[c] * inv_n;
    float var = colsq[c] * inv_n - mean * mean;  // biased (torch BN)
    float istd = rsqrtf(var + 1e-5f);
    float sc = gamma[c] * istd;
    scale[c] = sc;
    shift[c] = beta[c] - mean * sc;
  }
}

// ---------------------------------------------------------------------------
// Kernel 4: apply BN elementwise (float4)
// ---------------------------------------------------------------------------
__global__ __launch_bounds__(256) void bn_apply(
    float* __restrict__ out, const float* __restrict__ scale,
    const float* __restrict__ shift, long long n4) {
  long long i = (long long)blockIdx.x * blockDim.x + threadIdx.x;
  if (i >= n4) return;
  float4 v = ((float4*)out)[i];
  int c = (int)((i * 4) & (H - 1));
  v.x = fmaf(v.x, scale[c + 0], shift[c + 0]);
  v.y = fmaf(v.y, scale[c + 1], shift[c + 1]);
  v.z = fmaf(v.z, scale[c + 2], shift[c + 2]);
  v.w = fmaf(v.w, scale[c + 3], shift[c + 3]);
  ((float4*)out)[i] = v;
}

extern "C" void kernel_launch(void* const* d_in, const int* in_sizes, int n_in,
                              void* d_out, int out_size, void* d_ws, size_t ws_size,
                              hipStream_t stream) {
  const float* x     = (const float*)d_in[0];
  const void*  ei    = d_in[1];
  const float* Wl    = (const float*)d_in[2];
  const float* bl    = (const float*)d_in[3];
  const float* Wr    = (const float*)d_in[4];
  const float* gamma = (const float*)d_in[5];
  const float* beta  = (const float*)d_in[6];
  float* out = (float*)d_out;

  const int n = in_sizes[0] / F;   // 100000 (divisible by 16)
  const int E = in_sizes[1] / 2;   // 1600000

  // ws layout: [flag:int][pad to 256B][deg: n floats][colsum:128][colsq:128][scale:128][shift:128]
  char* ws = (char*)d_ws;
  int* flag = (int*)ws;
  float* deg    = (float*)(ws + 256);
  float* colsum = deg + n;
  float* colsq  = colsum + H;
  float* scale  = colsq + H;
  float* shift  = scale + H;
  size_t ws_used = 256 + (size_t)n * 4 + 4 * H * 4;

  hipMemsetAsync(d_out, 0, (size_t)out_size * sizeof(float), stream);
  hipMemsetAsync(d_ws, 0, ws_used, stream);

  detect_dtype<<<1, 64, 0, stream>>>((const unsigned*)ei, flag);

  long long sthreads = (long long)E * 32;
  int sblocks = (int)((sthreads + 255) / 256);
  scatter_mean<<<sblocks, 256, 0, stream>>>(x, ei, flag, out, deg, E);

  fused_gemm<<<n / 16, 256, 0, stream>>>(x, Wl, bl, Wr, deg, out, colsum, colsq);

  bn_stats<<<1, 128, 0, stream>>>(colsum, colsq, gamma, beta, scale, shift, n);

  long long n4 = (long long)n * H / 4;
  bn_apply<<<(int)((n4 + 255) / 256), 256, 0, stream>>>(out, scale, shift, n4);
}

// Round 2
// 611.222 us; speedup vs baseline: 4.8539x; 4.8539x over previous
//
#include <hip/hip_runtime.h>
#include <hip/hip_bf16.h>

static constexpr int F = 128;
static constexpr int H = 128;

// ---------------------------------------------------------------------------
// Kernel 0: detect whether edge_index is int64 (little-endian) or int32.
// Values are < 100000 < 2^17, so int64 layout has every odd 32-bit word == 0.
// ---------------------------------------------------------------------------
__global__ void detect_dtype(const unsigned* __restrict__ ei, int* __restrict__ flag) {
  if (blockIdx.x == 0 && threadIdx.x == 0) {
    int is64 = 1;
    for (int i = 0; i < 64; ++i) {
      if (ei[2 * i + 1] != 0u) { is64 = 0; break; }
    }
    *flag = is64;
  }
}

__device__ __forceinline__ int load_idx(const void* eiv, int is64, long long pos) {
  return is64 ? (int)((const long long*)eiv)[pos] : ((const int*)eiv)[pos];
}

// ---------------------------------------------------------------------------
// CSR build: degree count (int atomics, L2-resident counters)
// ---------------------------------------------------------------------------
__global__ __launch_bounds__(256) void deg_count(const void* __restrict__ eiv,
                                                 const int* __restrict__ flag,
                                                 int* __restrict__ degi, int E) {
  int e = blockIdx.x * blockDim.x + threadIdx.x;
  if (e >= E) return;
  int dst = load_idx(eiv, *flag, (long long)E + e);
  atomicAdd(&degi[dst], 1);
}

// ---------------------------------------------------------------------------
// 3-kernel exclusive prefix scan over degi[n] -> offsets[n+1], cursor copy
// ---------------------------------------------------------------------------
__global__ __launch_bounds__(256) void scan1(const int* __restrict__ degi,
                                             int* __restrict__ offsets,
                                             int* __restrict__ blocksum, int n) {
  __shared__ int sm[256];
  int idx = blockIdx.x * 256 + threadIdx.x;
  int v = (idx < n) ? degi[idx] : 0;
  sm[threadIdx.x] = v;
  __syncthreads();
  #pragma unroll
  for (int off = 1; off < 256; off <<= 1) {
    int t = (threadIdx.x >= off) ? sm[threadIdx.x - off] : 0;
    __syncthreads();
    sm[threadIdx.x] += t;
    __syncthreads();
  }
  if (idx < n) offsets[idx] = sm[threadIdx.x] - v;  // exclusive within block
  if (threadIdx.x == 255) blocksum[blockIdx.x] = sm[255];
}

__global__ __launch_bounds__(512) void scan2(const int* __restrict__ blocksum,
                                             int* __restrict__ blockoff, int nb) {
  __shared__ int sm[512];
  int v = ((int)threadIdx.x < nb) ? blocksum[threadIdx.x] : 0;
  sm[threadIdx.x] = v;
  __syncthreads();
  #pragma unroll
  for (int off = 1; off < 512; off <<= 1) {
    int t = (threadIdx.x >= (unsigned)off) ? sm[threadIdx.x - off] : 0;
    __syncthreads();
    sm[threadIdx.x] += t;
    __syncthreads();
  }
  if ((int)threadIdx.x < nb) blockoff[threadIdx.x] = sm[threadIdx.x] - v;
}

__global__ __launch_bounds__(256) void scan3(int* __restrict__ offsets,
                                             const int* __restrict__ blockoff,
                                             int* __restrict__ cursor, int n, int E) {
  int idx = blockIdx.x * 256 + threadIdx.x;
  if (idx >= n) return;
  int off = offsets[idx] + blockoff[idx >> 8];
  offsets[idx] = off;
  cursor[idx] = off;
  if (idx == 0) offsets[n] = E;
}

// ---------------------------------------------------------------------------
// Bucket fill: csr_src[pos(dst)++] = src  (int atomics on L2-resident cursors)
// ---------------------------------------------------------------------------
__global__ __launch_bounds__(256) void bucket_fill(const void* __restrict__ eiv,
                                                   const int* __restrict__ flag,
                                                   int* __restrict__ cursor,
                                                   int* __restrict__ csr_src, int E) {
  int e = blockIdx.x * blockDim.x + threadIdx.x;
  if (e >= E) return;
  int is64 = *flag;
  int src = load_idx(eiv, is64, e);
  int dst = load_idx(eiv, is64, (long long)E + e);
  int pos = atomicAdd(&cursor[dst], 1);
  csr_src[pos] = src;
}

// ---------------------------------------------------------------------------
// Gather + mean: one wave per node; 64 lanes x float2 = full 512B row/load.
// Writes the meaned aggregation into out (d_out reused as agg buffer).
// ---------------------------------------------------------------------------
__global__ __launch_bounds__(256) void gather_mean(const float* __restrict__ x,
                                                   const int* __restrict__ offsets,
                                                   const int* __restrict__ csr_src,
                                                   float* __restrict__ out, int n) {
  int node = (int)(((long long)blockIdx.x * blockDim.x + threadIdx.x) >> 6);
  int lane = threadIdx.x & 63;
  if (node >= n) return;
  int s = offsets[node], e = offsets[node + 1];
  float ax = 0.0f, ay = 0.0f, bx = 0.0f, by = 0.0f;
  int j = s;
  for (; j + 1 < e; j += 2) {  // 2-deep unroll for memory-level parallelism
    int s0 = csr_src[j], s1 = csr_src[j + 1];
    float2 v0 = *(const float2*)(x + (size_t)s0 * F + lane * 2);
    float2 v1 = *(const float2*)(x + (size_t)s1 * F + lane * 2);
    ax += v0.x; ay += v0.y;
    bx += v1.x; by += v1.y;
  }
  if (j < e) {
    int s0 = csr_src[j];
    float2 v0 = *(const float2*)(x + (size_t)s0 * F + lane * 2);
    ax += v0.x; ay += v0.y;
  }
  float inv = 1.0f / fmaxf((float)(e - s), 1.0f);
  float2 r; r.x = (ax + bx) * inv; r.y = (ay + by) * inv;
  *(float2*)(out + (size_t)node * H + lane * 2) = r;
}

// ---------------------------------------------------------------------------
// Fallback path (small ws): atomic scatter + deg, then divide.
// ---------------------------------------------------------------------------
__global__ __launch_bounds__(256) void scatter_mean(
    const float* __restrict__ x, const void* __restrict__ eiv,
    const int* __restrict__ flag, float* __restrict__ agg,
    float* __restrict__ deg, int E) {
  long long gid = (long long)blockIdx.x * blockDim.x + threadIdx.x;
  int e = (int)(gid >> 5);
  int ch = (int)(gid & 31);
  if (e >= E) return;
  int is64 = *flag;
  int src = load_idx(eiv, is64, e);
  int dst = load_idx(eiv, is64, (long long)E + e);
  float4 v = *(const float4*)(x + (size_t)src * F + ch * 4);
  float* a = agg + (size_t)dst * H + ch * 4;
  atomicAdd(a + 0, v.x);
  atomicAdd(a + 1, v.y);
  atomicAdd(a + 2, v.z);
  atomicAdd(a + 3, v.w);
  if (ch == 0) atomicAdd(deg + dst, 1.0f);
}

__global__ __launch_bounds__(256) void divide_deg(float* __restrict__ out,
                                                  const float* __restrict__ deg,
                                                  long long n4) {
  long long i = (long long)blockIdx.x * blockDim.x + threadIdx.x;
  if (i >= n4) return;
  int node = (int)(i >> 5);  // 32 float4 per row
  float s = 1.0f / fmaxf(deg[node], 1.0f);
  float4 v = ((float4*)out)[i];
  v.x *= s; v.y *= s; v.z *= s; v.w *= s;
  ((float4*)out)[i] = v;
}

// ---------------------------------------------------------------------------
// fused GEMM: out = relu(L2norm_row(agg@Wl + bl + x@Wr)), + column stats
// agg read in-place from out. 16 rows/block, 256 threads.
// ---------------------------------------------------------------------------
__global__ __launch_bounds__(256) void fused_gemm(
    const float* __restrict__ x, const float* __restrict__ Wl,
    const float* __restrict__ bl, const float* __restrict__ Wr,
    float* __restrict__ out, float* __restrict__ colsum, float* __restrict__ colsq) {
  __shared__ float As[16][256];
  __shared__ float rp[4][8];
  __shared__ float rscale[16];
  __shared__ float cs[128], cs2[128];

  const int t = threadIdx.x;
  const int i0 = blockIdx.x * 16;

  // Stage A-tile: As[r][0..127] = agg row (already meaned), [128..255] = x row
  #pragma unroll
  for (int it = 0; it < 2; ++it) {
    int idx = (it * 256 + t) * 4;  // 0..2044
    int r = idx >> 7, c = idx & 127;
    float4 va = *(const float4*)(out + (size_t)(i0 + r) * H + c);
    As[r][c + 0] = va.x; As[r][c + 1] = va.y;
    As[r][c + 2] = va.z; As[r][c + 3] = va.w;
    float4 vx = *(const float4*)(x + (size_t)(i0 + r) * F + c);
    As[r][128 + c + 0] = vx.x; As[r][128 + c + 1] = vx.y;
    As[r][128 + c + 2] = vx.z; As[r][128 + c + 3] = vx.w;
  }
  __syncthreads();

  const int c = t & 127;
  const int half = t >> 7;
  float acc[8];
  #pragma unroll
  for (int r = 0; r < 8; ++r) acc[r] = 0.0f;

  #pragma unroll 4
  for (int k = 0; k < 128; ++k) {
    float w = Wl[k * H + c];
    #pragma unroll
    for (int r = 0; r < 8; ++r) acc[r] = fmaf(As[half * 8 + r][k], w, acc[r]);
  }
  #pragma unroll 4
  for (int k = 0; k < 128; ++k) {
    float w = Wr[k * H + c];
    #pragma unroll
    for (int r = 0; r < 8; ++r) acc[r] = fmaf(As[half * 8 + r][128 + k], w, acc[r]);
  }
  const float bias = bl[c];
  #pragma unroll
  for (int r = 0; r < 8; ++r) acc[r] += bias;

  // Row L2 norms: each row's 128 values live across 2 waves (same `half`).
  float sq[8];
  #pragma unroll
  for (int r = 0; r < 8; ++r) sq[r] = acc[r] * acc[r];
  #pragma unroll
  for (int off = 32; off > 0; off >>= 1) {
    #pragma unroll
    for (int r = 0; r < 8; ++r) sq[r] += __shfl_down(sq[r], off, 64);
  }
  const int wv = t >> 6;
  if ((t & 63) == 0) {
    #pragma unroll
    for (int r = 0; r < 8; ++r) rp[wv][r] = sq[r];
  }
  __syncthreads();
  if (t < 16) {
    int base = (t >> 3) * 2, rr = t & 7;
    float s = rp[base][rr] + rp[base + 1][rr];
    rscale[t] = 1.0f / fmaxf(sqrtf(s), 1e-12f);
  }
  __syncthreads();

  float csum = 0.0f, csq = 0.0f;
  #pragma unroll
  for (int r = 0; r < 8; ++r) {
    float v = fmaxf(acc[r] * rscale[half * 8 + r], 0.0f);
    out[(size_t)(i0 + half * 8 + r) * H + c] = v;
    csum += v;
    csq += v * v;
  }
  if (half == 1) { cs[c] = csum; cs2[c] = csq; }
  __syncthreads();
  if (half == 0) {
    atomicAdd(&colsum[c], csum + cs[c]);
    atomicAdd(&colsq[c], csq + cs2[c]);
  }
}

__global__ void bn_stats(const float* __restrict__ colsum, const float* __restrict__ colsq,
                         const float* __restrict__ gamma, const float* __restrict__ beta,
                         float* __restrict__ scale, float* __restrict__ shift, int n) {
  int c = threadIdx.x;
  if (c < H) {
    float inv_n = 1.0f / (float)n;
    float mean = colsum[c] * inv_n;
    float var = colsq[c] * inv_n - mean * mean;  // biased (torch BN)
    float istd = rsqrtf(var + 1e-5f);
    float sc = gamma[c] * istd;
    scale[c] = sc;
    shift[c] = beta[c] - mean * sc;
  }
}

__global__ __launch_bounds__(256) void bn_apply(
    float* __restrict__ out, const float* __restrict__ scale,
    const float* __restrict__ shift, long long n4) {
  long long i = (long long)blockIdx.x * blockDim.x + threadIdx.x;
  if (i >= n4) return;
  float4 v = ((float4*)out)[i];
  int c = (int)((i * 4) & (H - 1));
  v.x = fmaf(v.x, scale[c + 0], shift[c + 0]);
  v.y = fmaf(v.y, scale[c + 1], shift[c + 1]);
  v.z = fmaf(v.z, scale[c + 2], shift[c + 2]);
  v.w = fmaf(v.w, scale[c + 3], shift[c + 3]);
  ((float4*)out)[i] = v;
}

extern "C" void kernel_launch(void* const* d_in, const int* in_sizes, int n_in,
                              void* d_out, int out_size, void* d_ws, size_t ws_size,
                              hipStream_t stream) {
  const float* x     = (const float*)d_in[0];
  const void*  ei    = d_in[1];
  const float* Wl    = (const float*)d_in[2];
  const float* bl    = (const float*)d_in[3];
  const float* Wr    = (const float*)d_in[4];
  const float* gamma = (const float*)d_in[5];
  const float* beta  = (const float*)d_in[6];
  float* out = (float*)d_out;

  const int n = in_sizes[0] / F;   // 100000
  const int E = in_sizes[1] / 2;   // 1600000
  const int nb = (n + 255) / 256;  // scan blocks

  char* ws = (char*)d_ws;
  int* flag = (int*)ws;

  // CSR-path ws layout
  int*   degi     = (int*)(ws + 256);
  int*   offsets  = degi + n;          // n+1 ints
  int*   cursor   = offsets + n + 1;
  int*   blocksum = cursor + n;
  int*   blockoff = blocksum + nb;
  float* colsum   = (float*)(blockoff + nb);
  float* colsq    = colsum + H;
  float* scale    = colsq + H;
  float* shift    = scale + H;
  int*   csr_src  = (int*)(shift + H);
  size_t need = (size_t)((char*)(csr_src + E) - ws);

  const int eb = (E + 255) / 256;
  detect_dtype<<<1, 64, 0, stream>>>((const unsigned*)ei, flag);

  if (ws_size >= need) {
    // zero degi + colsum/colsq (contiguous stretch from degi to shift end is
    // cheap: n+2*nb+... ints ~ 1.2 MB; just zero degi and the 4 stat arrays)
    hipMemsetAsync(degi, 0, (size_t)n * 4, stream);
    hipMemsetAsync(colsum, 0, 2 * H * 4, stream);

    deg_count<<<eb, 256, 0, stream>>>(ei, flag, degi, E);
    scan1<<<nb, 256, 0, stream>>>(degi, offsets, blocksum, n);
    scan2<<<1, 512, 0, stream>>>(blocksum, blockoff, nb);
    scan3<<<nb, 256, 0, stream>>>(offsets, blockoff, cursor, n, E);
    bucket_fill<<<eb, 256, 0, stream>>>(ei, flag, cursor, csr_src, E);

    long long gthreads = (long long)n * 64;
    gather_mean<<<(int)((gthreads + 255) / 256), 256, 0, stream>>>(
        x, offsets, csr_src, out, n);
  } else {
    // Fallback: atomic scatter (slow but correct under tiny ws)
    float* deg     = (float*)(ws + 256);
    colsum = deg + n; colsq = colsum + H; scale = colsq + H; shift = scale + H;
    hipMemsetAsync(d_out, 0, (size_t)out_size * sizeof(float), stream);
    hipMemsetAsync(deg, 0, (size_t)n * 4 + 4 * H * 4, stream);
    long long sthreads = (long long)E * 32;
    scatter_mean<<<(int)((sthreads + 255) / 256), 256, 0, stream>>>(x, ei, flag, out, deg, E);
    long long n4 = (long long)n * H / 4;
    divide_deg<<<(int)((n4 + 255) / 256), 256, 0, stream>>>(out, deg, n4);
  }

  fused_gemm<<<n / 16, 256, 0, stream>>>(x, Wl, bl, Wr, out, colsum, colsq);
  bn_stats<<<1, 128, 0, stream>>>(colsum, colsq, gamma, beta, scale, shift, n);
  long long n4 = (long long)n * H / 4;
  bn_apply<<<(int)((n4 + 255) / 256), 256, 0, stream>>>(out, scale, shift, n4);
}

// Round 3
// 483.950 us; speedup vs baseline: 6.1304x; 1.2630x over previous
//
#include <hip/hip_runtime.h>
#include <hip/hip_bf16.h>

static constexpr int F = 128;
static constexpr int H = 128;

typedef __attribute__((ext_vector_type(8))) short short8;
typedef __attribute__((ext_vector_type(4))) float f32x4;

__device__ __forceinline__ unsigned short f2bf(float f) {
  union { float f; unsigned u; } a; a.f = f;
  unsigned r = a.u + 0x7FFF + ((a.u >> 16) & 1);
  return (unsigned short)(r >> 16);
}
__device__ __forceinline__ float bf2f(unsigned short h) {
  union { unsigned u; float f; } a; a.u = ((unsigned)h) << 16;
  return a.f;
}

// ---------------------------------------------------------------------------
// Kernel 0: detect int64 vs int32 edge_index (values < 2^17 -> hi words 0)
// ---------------------------------------------------------------------------
__global__ void detect_dtype(const unsigned* __restrict__ ei, int* __restrict__ flag) {
  if (blockIdx.x == 0 && threadIdx.x == 0) {
    int is64 = 1;
    for (int i = 0; i < 64; ++i) {
      if (ei[2 * i + 1] != 0u) { is64 = 0; break; }
    }
    *flag = is64;
  }
}

__device__ __forceinline__ int load_idx(const void* eiv, int is64, long long pos) {
  return is64 ? (int)((const long long*)eiv)[pos] : ((const int*)eiv)[pos];
}

// ---------------------------------------------------------------------------
// CSR build
// ---------------------------------------------------------------------------
__global__ __launch_bounds__(256) void deg_count(const void* __restrict__ eiv,
                                                 const int* __restrict__ flag,
                                                 int* __restrict__ degi, int E) {
  int e = blockIdx.x * blockDim.x + threadIdx.x;
  if (e >= E) return;
  int dst = load_idx(eiv, *flag, (long long)E + e);
  atomicAdd(&degi[dst], 1);
}

__global__ __launch_bounds__(256) void scan1(const int* __restrict__ degi,
                                             int* __restrict__ offsets,
                                             int* __restrict__ blocksum, int n) {
  __shared__ int sm[256];
  int idx = blockIdx.x * 256 + threadIdx.x;
  int v = (idx < n) ? degi[idx] : 0;
  sm[threadIdx.x] = v;
  __syncthreads();
  #pragma unroll
  for (int off = 1; off < 256; off <<= 1) {
    int t = (threadIdx.x >= off) ? sm[threadIdx.x - off] : 0;
    __syncthreads();
    sm[threadIdx.x] += t;
    __syncthreads();
  }
  if (idx < n) offsets[idx] = sm[threadIdx.x] - v;
  if (threadIdx.x == 255) blocksum[blockIdx.x] = sm[255];
}

__global__ __launch_bounds__(512) void scan2(const int* __restrict__ blocksum,
                                             int* __restrict__ blockoff, int nb) {
  __shared__ int sm[512];
  int v = ((int)threadIdx.x < nb) ? blocksum[threadIdx.x] : 0;
  sm[threadIdx.x] = v;
  __syncthreads();
  #pragma unroll
  for (int off = 1; off < 512; off <<= 1) {
    int t = (threadIdx.x >= (unsigned)off) ? sm[threadIdx.x - off] : 0;
    __syncthreads();
    sm[threadIdx.x] += t;
    __syncthreads();
  }
  if ((int)threadIdx.x < nb) blockoff[threadIdx.x] = sm[threadIdx.x] - v;
}

__global__ __launch_bounds__(256) void scan3(int* __restrict__ offsets,
                                             const int* __restrict__ blockoff,
                                             int* __restrict__ cursor, int n, int E) {
  int idx = blockIdx.x * 256 + threadIdx.x;
  if (idx >= n) return;
  int off = offsets[idx] + blockoff[idx >> 8];
  offsets[idx] = off;
  cursor[idx] = off;
  if (idx == 0) offsets[n] = E;
}

__global__ __launch_bounds__(256) void bucket_fill(const void* __restrict__ eiv,
                                                   const int* __restrict__ flag,
                                                   int* __restrict__ cursor,
                                                   int* __restrict__ csr_src, int E) {
  int e = blockIdx.x * blockDim.x + threadIdx.x;
  if (e >= E) return;
  int is64 = *flag;
  int src = load_idx(eiv, is64, e);
  int dst = load_idx(eiv, is64, (long long)E + e);
  int pos = atomicAdd(&cursor[dst], 1);
  csr_src[pos] = src;
}

// ---------------------------------------------------------------------------
// Gather + mean: one wave per node, float2/lane. agg -> d_out (f32).
// ---------------------------------------------------------------------------
__global__ __launch_bounds__(256) void gather_mean(const float* __restrict__ x,
                                                   const int* __restrict__ offsets,
                                                   const int* __restrict__ csr_src,
                                                   float* __restrict__ out, int n) {
  int node = (int)(((long long)blockIdx.x * blockDim.x + threadIdx.x) >> 6);
  int lane = threadIdx.x & 63;
  if (node >= n) return;
  int s = offsets[node], e = offsets[node + 1];
  float ax = 0.0f, ay = 0.0f, bx = 0.0f, by = 0.0f;
  int j = s;
  for (; j + 1 < e; j += 2) {
    int s0 = csr_src[j], s1 = csr_src[j + 1];
    float2 v0 = *(const float2*)(x + (size_t)s0 * F + lane * 2);
    float2 v1 = *(const float2*)(x + (size_t)s1 * F + lane * 2);
    ax += v0.x; ay += v0.y;
    bx += v1.x; by += v1.y;
  }
  if (j < e) {
    int s0 = csr_src[j];
    float2 v0 = *(const float2*)(x + (size_t)s0 * F + lane * 2);
    ax += v0.x; ay += v0.y;
  }
  float inv = 1.0f / fmaxf((float)(e - s), 1.0f);
  float2 r; r.x = (ax + bx) * inv; r.y = (ay + by) * inv;
  *(float2*)(out + (size_t)node * H + lane * 2) = r;
}

// ---------------------------------------------------------------------------
// prep_w: split Wl/Wr into bf16 hi/lo and store in MFMA fragment-blob order.
// Parts: 0=Wl_hi 1=Wl_lo 2=Wr_hi 3=Wr_lo. Blob (part,kc,nf) = 64 lanes x 8 bf16:
// elem(lane,j) = Wpart[kc*32 + (lane>>4)*8 + j][nf*16 + (lane&15)].
// ---------------------------------------------------------------------------
__global__ __launch_bounds__(256) void prep_w(const float* __restrict__ Wl,
                                              const float* __restrict__ Wr,
                                              unsigned short* __restrict__ Wcat) {
  int tid = blockIdx.x * 256 + threadIdx.x;
  if (tid >= 4 * 4 * 8 * 64) return;
  int lane = tid & 63;
  int nf   = (tid >> 6) & 7;
  int kc   = (tid >> 9) & 3;
  int part = tid >> 11;
  const float* W = (part < 2) ? Wl : Wr;
  bool lo = (part & 1);
  int ncol = nf * 16 + (lane & 15);
  int k0 = kc * 32 + (lane >> 4) * 8;
  unsigned short ov[8];
  #pragma unroll
  for (int j = 0; j < 8; ++j) {
    float v = W[(k0 + j) * H + ncol];
    unsigned short h = f2bf(v);
    ov[j] = lo ? f2bf(v - bf2f(h)) : h;
  }
  uint4 pack;
  pack.x = (unsigned)ov[0] | ((unsigned)ov[1] << 16);
  pack.y = (unsigned)ov[2] | ((unsigned)ov[3] << 16);
  pack.z = (unsigned)ov[4] | ((unsigned)ov[5] << 16);
  pack.w = (unsigned)ov[6] | ((unsigned)ov[7] << 16);
  *(uint4*)(Wcat + (size_t)tid * 8) = pack;
}

// ---------------------------------------------------------------------------
// mfma_gemm: out = relu(L2norm_row(agg@Wl + bl + x@Wr)) via split-bf16 MFMA,
// + column stats. BM=64 rows/block, 256 threads (4 waves), wave = 64r x 32c.
// A parts in LDS (XOR-swizzled 16B chunks), B fragments from Wcat (L2-hot).
// ---------------------------------------------------------------------------
__global__ __launch_bounds__(256) void mfma_gemm(
    const float* __restrict__ x, const unsigned short* __restrict__ Wcat,
    const float* __restrict__ bl, float* __restrict__ out,
    float* __restrict__ colsum, float* __restrict__ colsq, int n) {
  __shared__ unsigned short As[4][64][128];  // parts: 0=agg_hi 1=agg_lo 2=x_hi 3=x_lo
  __shared__ float rowsq[64][4];
  __shared__ float rscale[64];

  const int t = threadIdx.x;
  const int i0 = blockIdx.x * 64;

  // ---- stage A: 8 iters, 32 threads/row, float4/thread ----
  #pragma unroll
  for (int it = 0; it < 8; ++it) {
    int idx = it * 256 + t;          // 0..2047
    int r = idx >> 5;                // 0..63
    int c4 = (idx & 31) * 4;         // 0..124
    int row_g = i0 + r; if (row_g >= n) row_g = n - 1;
    int boff = (((c4 >> 3) ^ (r & 7)) << 3) + (c4 & 7);  // ushort offset in row
    float4 va = *(const float4*)(out + (size_t)row_g * H + c4);
    float4 vx = *(const float4*)(x + (size_t)row_g * H + c4);
    unsigned short h0 = f2bf(va.x), h1 = f2bf(va.y), h2 = f2bf(va.z), h3 = f2bf(va.w);
    uint2 hv = { (unsigned)h0 | ((unsigned)h1 << 16), (unsigned)h2 | ((unsigned)h3 << 16) };
    *(uint2*)&As[0][r][boff] = hv;
    unsigned short l0 = f2bf(va.x - bf2f(h0)), l1 = f2bf(va.y - bf2f(h1));
    unsigned short l2 = f2bf(va.z - bf2f(h2)), l3 = f2bf(va.w - bf2f(h3));
    uint2 lv = { (unsigned)l0 | ((unsigned)l1 << 16), (unsigned)l2 | ((unsigned)l3 << 16) };
    *(uint2*)&As[1][r][boff] = lv;
    h0 = f2bf(vx.x); h1 = f2bf(vx.y); h2 = f2bf(vx.z); h3 = f2bf(vx.w);
    uint2 hx = { (unsigned)h0 | ((unsigned)h1 << 16), (unsigned)h2 | ((unsigned)h3 << 16) };
    *(uint2*)&As[2][r][boff] = hx;
    l0 = f2bf(vx.x - bf2f(h0)); l1 = f2bf(vx.y - bf2f(h1));
    l2 = f2bf(vx.z - bf2f(h2)); l3 = f2bf(vx.w - bf2f(h3));
    uint2 lx = { (unsigned)l0 | ((unsigned)l1 << 16), (unsigned)l2 | ((unsigned)l3 << 16) };
    *(uint2*)&As[3][r][boff] = lx;
  }
  __syncthreads();

  const int w = t >> 6;
  const int lane = t & 63;

  f32x4 acc[4][2];
  #pragma unroll
  for (int rf = 0; rf < 4; ++rf)
    #pragma unroll
    for (int nfi = 0; nfi < 2; ++nfi)
      acc[rf][nfi] = (f32x4){0.f, 0.f, 0.f, 0.f};

  const int APM[6] = {0, 1, 0, 2, 3, 2};
  const int BPM[6] = {0, 0, 1, 2, 2, 3};

  #pragma unroll
  for (int pass = 0; pass < 6; ++pass) {
    const int ap = APM[pass], bp = BPM[pass];
    #pragma unroll
    for (int kc = 0; kc < 4; ++kc) {
      short8 bfr[2];
      #pragma unroll
      for (int nfi = 0; nfi < 2; ++nfi) {
        int blob = (bp * 4 + kc) * 8 + (w * 2 + nfi);
        bfr[nfi] = *(const short8*)(Wcat + (size_t)blob * 512 + lane * 8);
      }
      short8 afr[4];
      int chunk = kc * 4 + (lane >> 4);
      #pragma unroll
      for (int rf = 0; rf < 4; ++rf) {
        int row = rf * 16 + (lane & 15);
        afr[rf] = *(const short8*)(&As[ap][row][(chunk ^ (row & 7)) * 8]);
      }
      #pragma unroll
      for (int rf = 0; rf < 4; ++rf)
        #pragma unroll
        for (int nfi = 0; nfi < 2; ++nfi)
          acc[rf][nfi] = __builtin_amdgcn_mfma_f32_16x16x32_bf16(
              afr[rf], bfr[nfi], acc[rf][nfi], 0, 0, 0);
    }
  }

  // ---- epilogue: bias, row L2 norm, relu, store, col stats ----
  const float b0 = bl[w * 32 + (lane & 15)];
  const float b1 = bl[w * 32 + 16 + (lane & 15)];

  #pragma unroll
  for (int rf = 0; rf < 4; ++rf) {
    #pragma unroll
    for (int r4 = 0; r4 < 4; ++r4) {
      float v0 = acc[rf][0][r4] + b0;
      float v1 = acc[rf][1][r4] + b1;
      acc[rf][0][r4] = v0;
      acc[rf][1][r4] = v1;
      float sq = v0 * v0 + v1 * v1;
      sq += __shfl_xor(sq, 1, 64);
      sq += __shfl_xor(sq, 2, 64);
      sq += __shfl_xor(sq, 4, 64);
      sq += __shfl_xor(sq, 8, 64);
      if ((lane & 15) == 0) rowsq[rf * 16 + (lane >> 4) * 4 + r4][w] = sq;
    }
  }
  __syncthreads();
  if (t < 64) {
    float s = rowsq[t][0] + rowsq[t][1] + rowsq[t][2] + rowsq[t][3];
    rscale[t] = 1.0f / fmaxf(sqrtf(s), 1e-12f);
  }
  __syncthreads();

  float cs0 = 0.f, cq0 = 0.f, cs1 = 0.f, cq1 = 0.f;
  #pragma unroll
  for (int rf = 0; rf < 4; ++rf) {
    #pragma unroll
    for (int r4 = 0; r4 < 4; ++r4) {
      int rl = rf * 16 + (lane >> 4) * 4 + r4;
      int row = i0 + rl;
      float s = rscale[rl];
      float u0 = fmaxf(acc[rf][0][r4] * s, 0.f);
      float u1 = fmaxf(acc[rf][1][r4] * s, 0.f);
      if (row < n) {
        out[(size_t)row * H + w * 32 + (lane & 15)] = u0;
        out[(size_t)row * H + w * 32 + 16 + (lane & 15)] = u1;
        cs0 += u0; cq0 += u0 * u0;
        cs1 += u1; cq1 += u1 * u1;
      }
    }
  }
  cs0 += __shfl_xor(cs0, 16, 64); cs0 += __shfl_xor(cs0, 32, 64);
  cq0 += __shfl_xor(cq0, 16, 64); cq0 += __shfl_xor(cq0, 32, 64);
  cs1 += __shfl_xor(cs1, 16, 64); cs1 += __shfl_xor(cs1, 32, 64);
  cq1 += __shfl_xor(cq1, 16, 64); cq1 += __shfl_xor(cq1, 32, 64);
  if (lane < 16) {
    atomicAdd(&colsum[w * 32 + lane], cs0);
    atomicAdd(&colsq[w * 32 + lane], cq0);
    atomicAdd(&colsum[w * 32 + 16 + lane], cs1);
    atomicAdd(&colsq[w * 32 + 16 + lane], cq1);
  }
}

// ---------------------------------------------------------------------------
// Fallback path (small ws): atomic scatter + divide + scalar fused gemm.
// ---------------------------------------------------------------------------
__global__ __launch_bounds__(256) void scatter_mean(
    const float* __restrict__ x, const void* __restrict__ eiv,
    const int* __restrict__ flag, float* __restrict__ agg,
    float* __restrict__ deg, int E) {
  long long gid = (long long)blockIdx.x * blockDim.x + threadIdx.x;
  int e = (int)(gid >> 5);
  int ch = (int)(gid & 31);
  if (e >= E) return;
  int is64 = *flag;
  int src = load_idx(eiv, is64, e);
  int dst = load_idx(eiv, is64, (long long)E + e);
  float4 v = *(const float4*)(x + (size_t)src * F + ch * 4);
  float* a = agg + (size_t)dst * H + ch * 4;
  atomicAdd(a + 0, v.x);
  atomicAdd(a + 1, v.y);
  atomicAdd(a + 2, v.z);
  atomicAdd(a + 3, v.w);
  if (ch == 0) atomicAdd(deg + dst, 1.0f);
}

__global__ __launch_bounds__(256) void divide_deg(float* __restrict__ out,
                                                  const float* __restrict__ deg,
                                                  long long n4) {
  long long i = (long long)blockIdx.x * blockDim.x + threadIdx.x;
  if (i >= n4) return;
  int node = (int)(i >> 5);
  float s = 1.0f / fmaxf(deg[node], 1.0f);
  float4 v = ((float4*)out)[i];
  v.x *= s; v.y *= s; v.z *= s; v.w *= s;
  ((float4*)out)[i] = v;
}

__global__ __launch_bounds__(256) void fused_gemm(
    const float* __restrict__ x, const float* __restrict__ Wl,
    const float* __restrict__ bl, const float* __restrict__ Wr,
    float* __restrict__ out, float* __restrict__ colsum, float* __restrict__ colsq) {
  __shared__ float As[16][256];
  __shared__ float rp[4][8];
  __shared__ float rscale[16];
  __shared__ float cs[128], cs2[128];

  const int t = threadIdx.x;
  const int i0 = blockIdx.x * 16;

  #pragma unroll
  for (int it = 0; it < 2; ++it) {
    int idx = (it * 256 + t) * 4;
    int r = idx >> 7, c = idx & 127;
    float4 va = *(const float4*)(out + (size_t)(i0 + r) * H + c);
    As[r][c + 0] = va.x; As[r][c + 1] = va.y;
    As[r][c + 2] = va.z; As[r][c + 3] = va.w;
    float4 vx = *(const float4*)(x + (size_t)(i0 + r) * F + c);
    As[r][128 + c + 0] = vx.x; As[r][128 + c + 1] = vx.y;
    As[r][128 + c + 2] = vx.z; As[r][128 + c + 3] = vx.w;
  }
  __syncthreads();

  const int c = t & 127;
  const int half = t >> 7;
  float acc[8];
  #pragma unroll
  for (int r = 0; r < 8; ++r) acc[r] = 0.0f;

  #pragma unroll 4
  for (int k = 0; k < 128; ++k) {
    float w = Wl[k * H + c];
    #pragma unroll
    for (int r = 0; r < 8; ++r) acc[r] = fmaf(As[half * 8 + r][k], w, acc[r]);
  }
  #pragma unroll 4
  for (int k = 0; k < 128; ++k) {
    float w = Wr[k * H + c];
    #pragma unroll
    for (int r = 0; r < 8; ++r) acc[r] = fmaf(As[half * 8 + r][128 + k], w, acc[r]);
  }
  const float bias = bl[c];
  #pragma unroll
  for (int r = 0; r < 8; ++r) acc[r] += bias;

  float sq[8];
  #pragma unroll
  for (int r = 0; r < 8; ++r) sq[r] = acc[r] * acc[r];
  #pragma unroll
  for (int off = 32; off > 0; off >>= 1) {
    #pragma unroll
    for (int r = 0; r < 8; ++r) sq[r] += __shfl_down(sq[r], off, 64);
  }
  const int wv = t >> 6;
  if ((t & 63) == 0) {
    #pragma unroll
    for (int r = 0; r < 8; ++r) rp[wv][r] = sq[r];
  }
  __syncthreads();
  if (t < 16) {
    int base = (t >> 3) * 2, rr = t & 7;
    float s = rp[base][rr] + rp[base + 1][rr];
    rscale[t] = 1.0f / fmaxf(sqrtf(s), 1e-12f);
  }
  __syncthreads();

  float csum = 0.0f, csq = 0.0f;
  #pragma unroll
  for (int r = 0; r < 8; ++r) {
    float v = fmaxf(acc[r] * rscale[half * 8 + r], 0.0f);
    out[(size_t)(i0 + half * 8 + r) * H + c] = v;
    csum += v;
    csq += v * v;
  }
  if (half == 1) { cs[c] = csum; cs2[c] = csq; }
  __syncthreads();
  if (half == 0) {
    atomicAdd(&colsum[c], csum + cs[c]);
    atomicAdd(&colsq[c], csq + cs2[c]);
  }
}

__global__ void bn_stats(const float* __restrict__ colsum, const float* __restrict__ colsq,
                         const float* __restrict__ gamma, const float* __restrict__ beta,
                         float* __restrict__ scale, float* __restrict__ shift, int n) {
  int c = threadIdx.x;
  if (c < H) {
    float inv_n = 1.0f / (float)n;
    float mean = colsum[c] * inv_n;
    float var = colsq[c] * inv_n - mean * mean;  // biased (torch BN)
    float istd = rsqrtf(var + 1e-5f);
    float sc = gamma[c] * istd;
    scale[c] = sc;
    shift[c] = beta[c] - mean * sc;
  }
}

__global__ __launch_bounds__(256) void bn_apply(
    float* __restrict__ out, const float* __restrict__ scale,
    const float* __restrict__ shift, long long n4) {
  long long i = (long long)blockIdx.x * blockDim.x + threadIdx.x;
  if (i >= n4) return;
  float4 v = ((float4*)out)[i];
  int c = (int)((i * 4) & (H - 1));
  v.x = fmaf(v.x, scale[c + 0], shift[c + 0]);
  v.y = fmaf(v.y, scale[c + 1], shift[c + 1]);
  v.z = fmaf(v.z, scale[c + 2], shift[c + 2]);
  v.w = fmaf(v.w, scale[c + 3], shift[c + 3]);
  ((float4*)out)[i] = v;
}

extern "C" void kernel_launch(void* const* d_in, const int* in_sizes, int n_in,
                              void* d_out, int out_size, void* d_ws, size_t ws_size,
                              hipStream_t stream) {
  const float* x     = (const float*)d_in[0];
  const void*  ei    = d_in[1];
  const float* Wl    = (const float*)d_in[2];
  const float* bl    = (const float*)d_in[3];
  const float* Wr    = (const float*)d_in[4];
  const float* gamma = (const float*)d_in[5];
  const float* beta  = (const float*)d_in[6];
  float* out = (float*)d_out;

  const int n = in_sizes[0] / F;   // 100000
  const int E = in_sizes[1] / 2;   // 1600000
  const int nb = (n + 255) / 256;

  char* ws = (char*)d_ws;
  int* flag = (int*)ws;

  // CSR-path ws layout: [flag pad 256][Wcat 128KB][degi n][offsets n+1][cursor n]
  //                     [blocksum nb][blockoff nb][stats 4*128][csr_src E]
  unsigned short* Wcat = (unsigned short*)(ws + 256);
  int*   degi     = (int*)(ws + 256 + 4 * 128 * 128 * 2);
  int*   offsets  = degi + n;
  int*   cursor   = offsets + n + 1;
  int*   blocksum = cursor + n;
  int*   blockoff = blocksum + nb;
  float* colsum   = (float*)(blockoff + nb);
  float* colsq    = colsum + H;
  float* scale    = colsq + H;
  float* shift    = scale + H;
  int*   csr_src  = (int*)(shift + H);
  size_t need = (size_t)((char*)(csr_src + E) - ws);

  const int eb = (E + 255) / 256;
  detect_dtype<<<1, 64, 0, stream>>>((const unsigned*)ei, flag);

  if (ws_size >= need) {
    hipMemsetAsync(degi, 0, (size_t)n * 4, stream);
    hipMemsetAsync(colsum, 0, 2 * H * 4, stream);

    prep_w<<<32, 256, 0, stream>>>(Wl, Wr, Wcat);

    deg_count<<<eb, 256, 0, stream>>>(ei, flag, degi, E);
    scan1<<<nb, 256, 0, stream>>>(degi, offsets, blocksum, n);
    scan2<<<1, 512, 0, stream>>>(blocksum, blockoff, nb);
    scan3<<<nb, 256, 0, stream>>>(offsets, blockoff, cursor, n, E);
    bucket_fill<<<eb, 256, 0, stream>>>(ei, flag, cursor, csr_src, E);

    long long gthreads = (long long)n * 64;
    gather_mean<<<(int)((gthreads + 255) / 256), 256, 0, stream>>>(
        x, offsets, csr_src, out, n);

    mfma_gemm<<<(n + 63) / 64, 256, 0, stream>>>(x, Wcat, bl, out, colsum, colsq, n);
  } else {
    float* deg = (float*)(ws + 256);
    colsum = deg + n; colsq = colsum + H; scale = colsq + H; shift = scale + H;
    hipMemsetAsync(d_out, 0, (size_t)out_size * sizeof(float), stream);
    hipMemsetAsync(deg, 0, (size_t)n * 4 + 4 * H * 4, stream);
    long long sthreads = (long long)E * 32;
    scatter_mean<<<(int)((sthreads + 255) / 256), 256, 0, stream>>>(x, ei, flag, out, deg, E);
    long long n4f = (long long)n * H / 4;
    divide_deg<<<(int)((n4f + 255) / 256), 256, 0, stream>>>(out, deg, n4f);
    fused_gemm<<<n / 16, 256, 0, stream>>>(x, Wl, bl, Wr, out, colsum, colsq);
  }

  bn_stats<<<1, 128, 0, stream>>>(colsum, colsq, gamma, beta, scale, shift, n);
  long long n4 = (long long)n * H / 4;
  bn_apply<<<(int)((n4 + 255) / 256), 256, 0, stream>>>(out, scale, shift, n4);
}

// Round 4
// 421.645 us; speedup vs baseline: 7.0363x; 1.1478x over previous
//
#include <hip/hip_runtime.h>
#include <hip/hip_bf16.h>

static constexpr int F = 128;
static constexpr int H = 128;

typedef __attribute__((ext_vector_type(8))) short short8;
typedef __attribute__((ext_vector_type(4))) float f32x4;

__device__ __forceinline__ unsigned short f2bf(float f) {
  union { float f; unsigned u; } a; a.f = f;
  unsigned r = a.u + 0x7FFF + ((a.u >> 16) & 1);
  return (unsigned short)(r >> 16);
}
__device__ __forceinline__ float bf2f(unsigned short h) {
  union { unsigned u; float f; } a; a.u = ((unsigned)h) << 16;
  return a.f;
}
__device__ __forceinline__ float bits2f(unsigned u) {
  union { unsigned u; float f; } a; a.u = u;
  return a.f;
}

// ---------------------------------------------------------------------------
// Kernel 0: detect int64 vs int32 edge_index (values < 2^17 -> hi words 0)
// ---------------------------------------------------------------------------
__global__ void detect_dtype(const unsigned* __restrict__ ei, int* __restrict__ flag) {
  if (blockIdx.x == 0 && threadIdx.x == 0) {
    int is64 = 1;
    for (int i = 0; i < 64; ++i) {
      if (ei[2 * i + 1] != 0u) { is64 = 0; break; }
    }
    *flag = is64;
  }
}

__device__ __forceinline__ int load_idx(const void* eiv, int is64, long long pos) {
  return is64 ? (int)((const long long*)eiv)[pos] : ((const int*)eiv)[pos];
}

// ---------------------------------------------------------------------------
// CSR build
// ---------------------------------------------------------------------------
__global__ __launch_bounds__(256) void deg_count(const void* __restrict__ eiv,
                                                 const int* __restrict__ flag,
                                                 int* __restrict__ degi, int E) {
  int e = blockIdx.x * blockDim.x + threadIdx.x;
  if (e >= E) return;
  int dst = load_idx(eiv, *flag, (long long)E + e);
  atomicAdd(&degi[dst], 1);
}

__global__ __launch_bounds__(256) void scan1(const int* __restrict__ degi,
                                             int* __restrict__ offsets,
                                             int* __restrict__ blocksum, int n) {
  __shared__ int sm[256];
  int idx = blockIdx.x * 256 + threadIdx.x;
  int v = (idx < n) ? degi[idx] : 0;
  sm[threadIdx.x] = v;
  __syncthreads();
  #pragma unroll
  for (int off = 1; off < 256; off <<= 1) {
    int t = (threadIdx.x >= off) ? sm[threadIdx.x - off] : 0;
    __syncthreads();
    sm[threadIdx.x] += t;
    __syncthreads();
  }
  if (idx < n) offsets[idx] = sm[threadIdx.x] - v;
  if (threadIdx.x == 255) blocksum[blockIdx.x] = sm[255];
}

__global__ __launch_bounds__(512) void scan2(const int* __restrict__ blocksum,
                                             int* __restrict__ blockoff, int nb) {
  __shared__ int sm[512];
  int v = ((int)threadIdx.x < nb) ? blocksum[threadIdx.x] : 0;
  sm[threadIdx.x] = v;
  __syncthreads();
  #pragma unroll
  for (int off = 1; off < 512; off <<= 1) {
    int t = (threadIdx.x >= (unsigned)off) ? sm[threadIdx.x - off] : 0;
    __syncthreads();
    sm[threadIdx.x] += t;
    __syncthreads();
  }
  if ((int)threadIdx.x < nb) blockoff[threadIdx.x] = sm[threadIdx.x] - v;
}

__global__ __launch_bounds__(256) void scan3(int* __restrict__ offsets,
                                             const int* __restrict__ blockoff,
                                             int* __restrict__ cursor, int n, int E) {
  int idx = blockIdx.x * 256 + threadIdx.x;
  if (idx >= n) return;
  int off = offsets[idx] + blockoff[idx >> 8];
  offsets[idx] = off;
  cursor[idx] = off;
  if (idx == 0) offsets[n] = E;
}

__global__ __launch_bounds__(256) void bucket_fill(const void* __restrict__ eiv,
                                                   const int* __restrict__ flag,
                                                   int* __restrict__ cursor,
                                                   int* __restrict__ csr_src, int E) {
  int e = blockIdx.x * blockDim.x + threadIdx.x;
  if (e >= E) return;
  int is64 = *flag;
  int src = load_idx(eiv, is64, e);
  int dst = load_idx(eiv, is64, (long long)E + e);
  int pos = atomicAdd(&cursor[dst], 1);
  csr_src[pos] = src;
}

// ---------------------------------------------------------------------------
// prep_w: split Wl/Wr into bf16 hi/lo in MFMA fragment-blob order.
// Parts: 0=Wl_hi 1=Wl_lo 2=Wr_hi 3=Wr_lo.
// elem(lane,j) = Wpart[kc*32 + (lane>>4)*8 + j][nf*16 + (lane&15)].
// ---------------------------------------------------------------------------
__global__ __launch_bounds__(256) void prep_w(const float* __restrict__ Wl,
                                              const float* __restrict__ Wr,
                                              unsigned short* __restrict__ Wcat) {
  int tid = blockIdx.x * 256 + threadIdx.x;
  if (tid >= 4 * 4 * 8 * 64) return;
  int lane = tid & 63;
  int nf   = (tid >> 6) & 7;
  int kc   = (tid >> 9) & 3;
  int part = tid >> 11;
  const float* W = (part < 2) ? Wl : Wr;
  bool lo = (part & 1);
  int ncol = nf * 16 + (lane & 15);
  int k0 = kc * 32 + (lane >> 4) * 8;
  unsigned short ov[8];
  #pragma unroll
  for (int j = 0; j < 8; ++j) {
    float v = W[(k0 + j) * H + ncol];
    unsigned short h = f2bf(v);
    ov[j] = lo ? f2bf(v - bf2f(h)) : h;
  }
  uint4 pack;
  pack.x = (unsigned)ov[0] | ((unsigned)ov[1] << 16);
  pack.y = (unsigned)ov[2] | ((unsigned)ov[3] << 16);
  pack.z = (unsigned)ov[4] | ((unsigned)ov[5] << 16);
  pack.w = (unsigned)ov[6] | ((unsigned)ov[7] << 16);
  *(uint4*)(Wcat + (size_t)tid * 8) = pack;
}

// ---------------------------------------------------------------------------
// ymat: Y = x @ Wl  (split-bf16 MFMA, 3 passes), output rounded to bf16.
// ---------------------------------------------------------------------------
__global__ __launch_bounds__(256) void ymat(
    const float* __restrict__ x, const unsigned short* __restrict__ Wcat,
    unsigned short* __restrict__ Y, int n) {
  __shared__ unsigned short As[2][64][128];  // x_hi, x_lo

  const int t = threadIdx.x;
  const int i0 = blockIdx.x * 64;

  #pragma unroll
  for (int it = 0; it < 8; ++it) {
    int idx = it * 256 + t;
    int r = idx >> 5;
    int c4 = (idx & 31) * 4;
    int row_g = i0 + r; if (row_g >= n) row_g = n - 1;
    int boff = (((c4 >> 3) ^ (r & 7)) << 3) + (c4 & 7);
    float4 vx = *(const float4*)(x + (size_t)row_g * F + c4);
    unsigned short h0 = f2bf(vx.x), h1 = f2bf(vx.y), h2 = f2bf(vx.z), h3 = f2bf(vx.w);
    uint2 hv = { (unsigned)h0 | ((unsigned)h1 << 16), (unsigned)h2 | ((unsigned)h3 << 16) };
    *(uint2*)&As[0][r][boff] = hv;
    unsigned short l0 = f2bf(vx.x - bf2f(h0)), l1 = f2bf(vx.y - bf2f(h1));
    unsigned short l2 = f2bf(vx.z - bf2f(h2)), l3 = f2bf(vx.w - bf2f(h3));
    uint2 lv = { (unsigned)l0 | ((unsigned)l1 << 16), (unsigned)l2 | ((unsigned)l3 << 16) };
    *(uint2*)&As[1][r][boff] = lv;
  }
  __syncthreads();

  const int w = t >> 6;
  const int lane = t & 63;

  f32x4 acc[4][2];
  #pragma unroll
  for (int rf = 0; rf < 4; ++rf)
    #pragma unroll
    for (int nfi = 0; nfi < 2; ++nfi)
      acc[rf][nfi] = (f32x4){0.f, 0.f, 0.f, 0.f};

  const int APM[3] = {0, 1, 0};
  const int BPM[3] = {0, 0, 1};   // Wl_hi, Wl_hi, Wl_lo

  #pragma unroll
  for (int pass = 0; pass < 3; ++pass) {
    const int ap = APM[pass], bp = BPM[pass];
    #pragma unroll
    for (int kc = 0; kc < 4; ++kc) {
      short8 bfr[2];
      #pragma unroll
      for (int nfi = 0; nfi < 2; ++nfi) {
        int blob = (bp * 4 + kc) * 8 + (w * 2 + nfi);
        bfr[nfi] = *(const short8*)(Wcat + (size_t)blob * 512 + lane * 8);
      }
      short8 afr[4];
      int chunk = kc * 4 + (lane >> 4);
      #pragma unroll
      for (int rf = 0; rf < 4; ++rf) {
        int row = rf * 16 + (lane & 15);
        afr[rf] = *(const short8*)(&As[ap][row][(chunk ^ (row & 7)) * 8]);
      }
      #pragma unroll
      for (int rf = 0; rf < 4; ++rf)
        #pragma unroll
        for (int nfi = 0; nfi < 2; ++nfi)
          acc[rf][nfi] = __builtin_amdgcn_mfma_f32_16x16x32_bf16(
              afr[rf], bfr[nfi], acc[rf][nfi], 0, 0, 0);
    }
  }

  #pragma unroll
  for (int rf = 0; rf < 4; ++rf) {
    #pragma unroll
    for (int r4 = 0; r4 < 4; ++r4) {
      int rl = rf * 16 + (lane >> 4) * 4 + r4;
      int row = i0 + rl;
      if (row < n) {
        Y[(size_t)row * H + w * 32 + (lane & 15)]      = f2bf(acc[rf][0][r4]);
        Y[(size_t)row * H + w * 32 + 16 + (lane & 15)] = f2bf(acc[rf][1][r4]);
      }
    }
  }
}

// ---------------------------------------------------------------------------
// gather_bf16: agg[node] = mean of Y[src] rows (bf16 in, f32 out to d_out).
// 2 nodes per wave (32 lanes each, uint2 = 4 bf16/lane), 4-deep unroll.
// ---------------------------------------------------------------------------
__global__ __launch_bounds__(256) void gather_bf16(
    const unsigned short* __restrict__ Y, const int* __restrict__ offsets,
    const int* __restrict__ csr_src, float* __restrict__ agg, int n) {
  long long gid = (long long)blockIdx.x * blockDim.x + threadIdx.x;
  int wave = (int)(gid >> 6);
  int lane = threadIdx.x & 63;
  int node = wave * 2 + (lane >> 5);
  if (node >= n) return;
  int c = (lane & 31) * 4;
  int s = offsets[node], e = offsets[node + 1];
  float acc[4][4];
  #pragma unroll
  for (int u = 0; u < 4; ++u)
    #pragma unroll
    for (int q = 0; q < 4; ++q) acc[u][q] = 0.0f;

  int j = s;
  for (; j + 3 < e; j += 4) {
    #pragma unroll
    for (int u = 0; u < 4; ++u) {
      int sj = csr_src[j + u];
      uint2 uv = *(const uint2*)(Y + (size_t)sj * H + c);
      acc[u][0] += bits2f(uv.x << 16);
      acc[u][1] += bits2f(uv.x & 0xFFFF0000u);
      acc[u][2] += bits2f(uv.y << 16);
      acc[u][3] += bits2f(uv.y & 0xFFFF0000u);
    }
  }
  for (; j < e; ++j) {
    int sj = csr_src[j];
    uint2 uv = *(const uint2*)(Y + (size_t)sj * H + c);
    acc[0][0] += bits2f(uv.x << 16);
    acc[0][1] += bits2f(uv.x & 0xFFFF0000u);
    acc[0][2] += bits2f(uv.y << 16);
    acc[0][3] += bits2f(uv.y & 0xFFFF0000u);
  }
  float inv = 1.0f / fmaxf((float)(e - s), 1.0f);
  float4 r;
  r.x = (acc[0][0] + acc[1][0] + acc[2][0] + acc[3][0]) * inv;
  r.y = (acc[0][1] + acc[1][1] + acc[2][1] + acc[3][1]) * inv;
  r.z = (acc[0][2] + acc[1][2] + acc[2][2] + acc[3][2]) * inv;
  r.w = (acc[0][3] + acc[1][3] + acc[2][3] + acc[3][3]) * inv;
  *(float4*)(agg + (size_t)node * H + c) = r;
}

// ---------------------------------------------------------------------------
// final_gemm: out = relu(L2norm_row(x@Wr + agg + bl)) + col stats.
// agg (= mean(Y[src]) = agg@Wl) read f32 from d_out, result written in place.
// ---------------------------------------------------------------------------
__global__ __launch_bounds__(256) void final_gemm(
    const float* __restrict__ x, const unsigned short* __restrict__ Wcat,
    const float* __restrict__ bl, float* __restrict__ out,
    float* __restrict__ colsum, float* __restrict__ colsq, int n) {
  __shared__ unsigned short As[2][64][128];  // x_hi, x_lo
  __shared__ float Ag[64][132];              // agg rows (padded vs bank conflict)
  __shared__ float rowsq[64][4];
  __shared__ float rscale[64];

  const int t = threadIdx.x;
  const int i0 = blockIdx.x * 64;

  #pragma unroll
  for (int it = 0; it < 8; ++it) {
    int idx = it * 256 + t;
    int r = idx >> 5;
    int c4 = (idx & 31) * 4;
    int row_g = i0 + r; if (row_g >= n) row_g = n - 1;
    int boff = (((c4 >> 3) ^ (r & 7)) << 3) + (c4 & 7);
    float4 vx = *(const float4*)(x + (size_t)row_g * F + c4);
    unsigned short h0 = f2bf(vx.x), h1 = f2bf(vx.y), h2 = f2bf(vx.z), h3 = f2bf(vx.w);
    uint2 hv = { (unsigned)h0 | ((unsigned)h1 << 16), (unsigned)h2 | ((unsigned)h3 << 16) };
    *(uint2*)&As[0][r][boff] = hv;
    unsigned short l0 = f2bf(vx.x - bf2f(h0)), l1 = f2bf(vx.y - bf2f(h1));
    unsigned short l2 = f2bf(vx.z - bf2f(h2)), l3 = f2bf(vx.w - bf2f(h3));
    uint2 lv = { (unsigned)l0 | ((unsigned)l1 << 16), (unsigned)l2 | ((unsigned)l3 << 16) };
    *(uint2*)&As[1][r][boff] = lv;
    float4 va = *(const float4*)(out + (size_t)row_g * H + c4);
    *(float4*)&Ag[r][c4] = va;
  }
  __syncthreads();

  const int w = t >> 6;
  const int lane = t & 63;

  f32x4 acc[4][2];
  #pragma unroll
  for (int rf = 0; rf < 4; ++rf)
    #pragma unroll
    for (int nfi = 0; nfi < 2; ++nfi)
      acc[rf][nfi] = (f32x4){0.f, 0.f, 0.f, 0.f};

  const int APM[3] = {0, 1, 0};
  const int BPM[3] = {2, 2, 3};   // Wr_hi, Wr_hi, Wr_lo

  #pragma unroll
  for (int pass = 0; pass < 3; ++pass) {
    const int ap = APM[pass], bp = BPM[pass];
    #pragma unroll
    for (int kc = 0; kc < 4; ++kc) {
      short8 bfr[2];
      #pragma unroll
      for (int nfi = 0; nfi < 2; ++nfi) {
        int blob = (bp * 4 + kc) * 8 + (w * 2 + nfi);
        bfr[nfi] = *(const short8*)(Wcat + (size_t)blob * 512 + lane * 8);
      }
      short8 afr[4];
      int chunk = kc * 4 + (lane >> 4);
      #pragma unroll
      for (int rf = 0; rf < 4; ++rf) {
        int row = rf * 16 + (lane & 15);
        afr[rf] = *(const short8*)(&As[ap][row][(chunk ^ (row & 7)) * 8]);
      }
      #pragma unroll
      for (int rf = 0; rf < 4; ++rf)
        #pragma unroll
        for (int nfi = 0; nfi < 2; ++nfi)
          acc[rf][nfi] = __builtin_amdgcn_mfma_f32_16x16x32_bf16(
              afr[rf], bfr[nfi], acc[rf][nfi], 0, 0, 0);
    }
  }

  const float b0 = bl[w * 32 + (lane & 15)];
  const float b1 = bl[w * 32 + 16 + (lane & 15)];

  #pragma unroll
  for (int rf = 0; rf < 4; ++rf) {
    #pragma unroll
    for (int r4 = 0; r4 < 4; ++r4) {
      int rl = rf * 16 + (lane >> 4) * 4 + r4;
      float v0 = acc[rf][0][r4] + b0 + Ag[rl][w * 32 + (lane & 15)];
      float v1 = acc[rf][1][r4] + b1 + Ag[rl][w * 32 + 16 + (lane & 15)];
      acc[rf][0][r4] = v0;
      acc[rf][1][r4] = v1;
      float sq = v0 * v0 + v1 * v1;
      sq += __shfl_xor(sq, 1, 64);
      sq += __shfl_xor(sq, 2, 64);
      sq += __shfl_xor(sq, 4, 64);
      sq += __shfl_xor(sq, 8, 64);
      if ((lane & 15) == 0) rowsq[rl][w] = sq;
    }
  }
  __syncthreads();
  if (t < 64) {
    float s = rowsq[t][0] + rowsq[t][1] + rowsq[t][2] + rowsq[t][3];
    rscale[t] = 1.0f / fmaxf(sqrtf(s), 1e-12f);
  }
  __syncthreads();

  float cs0 = 0.f, cq0 = 0.f, cs1 = 0.f, cq1 = 0.f;
  #pragma unroll
  for (int rf = 0; rf < 4; ++rf) {
    #pragma unroll
    for (int r4 = 0; r4 < 4; ++r4) {
      int rl = rf * 16 + (lane >> 4) * 4 + r4;
      int row = i0 + rl;
      float s = rscale[rl];
      float u0 = fmaxf(acc[rf][0][r4] * s, 0.f);
      float u1 = fmaxf(acc[rf][1][r4] * s, 0.f);
      if (row < n) {
        out[(size_t)row * H + w * 32 + (lane & 15)] = u0;
        out[(size_t)row * H + w * 32 + 16 + (lane & 15)] = u1;
        cs0 += u0; cq0 += u0 * u0;
        cs1 += u1; cq1 += u1 * u1;
      }
    }
  }
  cs0 += __shfl_xor(cs0, 16, 64); cs0 += __shfl_xor(cs0, 32, 64);
  cq0 += __shfl_xor(cq0, 16, 64); cq0 += __shfl_xor(cq0, 32, 64);
  cs1 += __shfl_xor(cs1, 16, 64); cs1 += __shfl_xor(cs1, 32, 64);
  cq1 += __shfl_xor(cq1, 16, 64); cq1 += __shfl_xor(cq1, 32, 64);
  if (lane < 16) {
    atomicAdd(&colsum[w * 32 + lane], cs0);
    atomicAdd(&colsq[w * 32 + lane], cq0);
    atomicAdd(&colsum[w * 32 + 16 + lane], cs1);
    atomicAdd(&colsq[w * 32 + 16 + lane], cq1);
  }
}

// ---------------------------------------------------------------------------
// Mid path (round-3): f32 gather + double MFMA gemm.
// ---------------------------------------------------------------------------
__global__ __launch_bounds__(256) void gather_mean(const float* __restrict__ x,
                                                   const int* __restrict__ offsets,
                                                   const int* __restrict__ csr_src,
                                                   float* __restrict__ out, int n) {
  int node = (int)(((long long)blockIdx.x * blockDim.x + threadIdx.x) >> 6);
  int lane = threadIdx.x & 63;
  if (node >= n) return;
  int s = offsets[node], e = offsets[node + 1];
  float ax = 0.0f, ay = 0.0f, bx = 0.0f, by = 0.0f;
  int j = s;
  for (; j + 1 < e; j += 2) {
    int s0 = csr_src[j], s1 = csr_src[j + 1];
    float2 v0 = *(const float2*)(x + (size_t)s0 * F + lane * 2);
    float2 v1 = *(const float2*)(x + (size_t)s1 * F + lane * 2);
    ax += v0.x; ay += v0.y;
    bx += v1.x; by += v1.y;
  }
  if (j < e) {
    int s0 = csr_src[j];
    float2 v0 = *(const float2*)(x + (size_t)s0 * F + lane * 2);
    ax += v0.x; ay += v0.y;
  }
  float inv = 1.0f / fmaxf((float)(e - s), 1.0f);
  float2 r; r.x = (ax + bx) * inv; r.y = (ay + by) * inv;
  *(float2*)(out + (size_t)node * H + lane * 2) = r;
}

__global__ __launch_bounds__(256) void mfma_gemm(
    const float* __restrict__ x, const unsigned short* __restrict__ Wcat,
    const float* __restrict__ bl, float* __restrict__ out,
    float* __restrict__ colsum, float* __restrict__ colsq, int n) {
  __shared__ unsigned short As[4][64][128];
  __shared__ float rowsq[64][4];
  __shared__ float rscale[64];

  const int t = threadIdx.x;
  const int i0 = blockIdx.x * 64;

  #pragma unroll
  for (int it = 0; it < 8; ++it) {
    int idx = it * 256 + t;
    int r = idx >> 5;
    int c4 = (idx & 31) * 4;
    int row_g = i0 + r; if (row_g >= n) row_g = n - 1;
    int boff = (((c4 >> 3) ^ (r & 7)) << 3) + (c4 & 7);
    float4 va = *(const float4*)(out + (size_t)row_g * H + c4);
    float4 vx = *(const float4*)(x + (size_t)row_g * H + c4);
    unsigned short h0 = f2bf(va.x), h1 = f2bf(va.y), h2 = f2bf(va.z), h3 = f2bf(va.w);
    uint2 hv = { (unsigned)h0 | ((unsigned)h1 << 16), (unsigned)h2 | ((unsigned)h3 << 16) };
    *(uint2*)&As[0][r][boff] = hv;
    unsigned short l0 = f2bf(va.x - bf2f(h0)), l1 = f2bf(va.y - bf2f(h1));
    unsigned short l2 = f2bf(va.z - bf2f(h2)), l3 = f2bf(va.w - bf2f(h3));
    uint2 lv = { (unsigned)l0 | ((unsigned)l1 << 16), (unsigned)l2 | ((unsigned)l3 << 16) };
    *(uint2*)&As[1][r][boff] = lv;
    h0 = f2bf(vx.x); h1 = f2bf(vx.y); h2 = f2bf(vx.z); h3 = f2bf(vx.w);
    uint2 hx = { (unsigned)h0 | ((unsigned)h1 << 16), (unsigned)h2 | ((unsigned)h3 << 16) };
    *(uint2*)&As[2][r][boff] = hx;
    l0 = f2bf(vx.x - bf2f(h0)); l1 = f2bf(vx.y - bf2f(h1));
    l2 = f2bf(vx.z - bf2f(h2)); l3 = f2bf(vx.w - bf2f(h3));
    uint2 lx = { (unsigned)l0 | ((unsigned)l1 << 16), (unsigned)l2 | ((unsigned)l3 << 16) };
    *(uint2*)&As[3][r][boff] = lx;
  }
  __syncthreads();

  const int w = t >> 6;
  const int lane = t & 63;

  f32x4 acc[4][2];
  #pragma unroll
  for (int rf = 0; rf < 4; ++rf)
    #pragma unroll
    for (int nfi = 0; nfi < 2; ++nfi)
      acc[rf][nfi] = (f32x4){0.f, 0.f, 0.f, 0.f};

  const int APM[6] = {0, 1, 0, 2, 3, 2};
  const int BPM[6] = {0, 0, 1, 2, 2, 3};

  #pragma unroll
  for (int pass = 0; pass < 6; ++pass) {
    const int ap = APM[pass], bp = BPM[pass];
    #pragma unroll
    for (int kc = 0; kc < 4; ++kc) {
      short8 bfr[2];
      #pragma unroll
      for (int nfi = 0; nfi < 2; ++nfi) {
        int blob = (bp * 4 + kc) * 8 + (w * 2 + nfi);
        bfr[nfi] = *(const short8*)(Wcat + (size_t)blob * 512 + lane * 8);
      }
      short8 afr[4];
      int chunk = kc * 4 + (lane >> 4);
      #pragma unroll
      for (int rf = 0; rf < 4; ++rf) {
        int row = rf * 16 + (lane & 15);
        afr[rf] = *(const short8*)(&As[ap][row][(chunk ^ (row & 7)) * 8]);
      }
      #pragma unroll
      for (int rf = 0; rf < 4; ++rf)
        #pragma unroll
        for (int nfi = 0; nfi < 2; ++nfi)
          acc[rf][nfi] = __builtin_amdgcn_mfma_f32_16x16x32_bf16(
              afr[rf], bfr[nfi], acc[rf][nfi], 0, 0, 0);
    }
  }

  const float b0 = bl[w * 32 + (lane & 15)];
  const float b1 = bl[w * 32 + 16 + (lane & 15)];

  #pragma unroll
  for (int rf = 0; rf < 4; ++rf) {
    #pragma unroll
    for (int r4 = 0; r4 < 4; ++r4) {
      float v0 = acc[rf][0][r4] + b0;
      float v1 = acc[rf][1][r4] + b1;
      acc[rf][0][r4] = v0;
      acc[rf][1][r4] = v1;
      float sq = v0 * v0 + v1 * v1;
      sq += __shfl_xor(sq, 1, 64);
      sq += __shfl_xor(sq, 2, 64);
      sq += __shfl_xor(sq, 4, 64);
      sq += __shfl_xor(sq, 8, 64);
      if ((lane & 15) == 0) rowsq[rf * 16 + (lane >> 4) * 4 + r4][w] = sq;
    }
  }
  __syncthreads();
  if (t < 64) {
    float s = rowsq[t][0] + rowsq[t][1] + rowsq[t][2] + rowsq[t][3];
    rscale[t] = 1.0f / fmaxf(sqrtf(s), 1e-12f);
  }
  __syncthreads();

  float cs0 = 0.f, cq0 = 0.f, cs1 = 0.f, cq1 = 0.f;
  #pragma unroll
  for (int rf = 0; rf < 4; ++rf) {
    #pragma unroll
    for (int r4 = 0; r4 < 4; ++r4) {
      int rl = rf * 16 + (lane >> 4) * 4 + r4;
      int row = i0 + rl;
      float s = rscale[rl];
      float u0 = fmaxf(acc[rf][0][r4] * s, 0.f);
      float u1 = fmaxf(acc[rf][1][r4] * s, 0.f);
      if (row < n) {
        out[(size_t)row * H + w * 32 + (lane & 15)] = u0;
        out[(size_t)row * H + w * 32 + 16 + (lane & 15)] = u1;
        cs0 += u0; cq0 += u0 * u0;
        cs1 += u1; cq1 += u1 * u1;
      }
    }
  }
  cs0 += __shfl_xor(cs0, 16, 64); cs0 += __shfl_xor(cs0, 32, 64);
  cq0 += __shfl_xor(cq0, 16, 64); cq0 += __shfl_xor(cq0, 32, 64);
  cs1 += __shfl_xor(cs1, 16, 64); cs1 += __shfl_xor(cs1, 32, 64);
  cq1 += __shfl_xor(cq1, 16, 64); cq1 += __shfl_xor(cq1, 32, 64);
  if (lane < 16) {
    atomicAdd(&colsum[w * 32 + lane], cs0);
    atomicAdd(&colsq[w * 32 + lane], cq0);
    atomicAdd(&colsum[w * 32 + 16 + lane], cs1);
    atomicAdd(&colsq[w * 32 + 16 + lane], cq1);
  }
}

// ---------------------------------------------------------------------------
// Fallback path (tiny ws): atomic scatter + divide + scalar fused gemm.
// ---------------------------------------------------------------------------
__global__ __launch_bounds__(256) void scatter_mean(
    const float* __restrict__ x, const void* __restrict__ eiv,
    const int* __restrict__ flag, float* __restrict__ agg,
    float* __restrict__ deg, int E) {
  long long gid = (long long)blockIdx.x * blockDim.x + threadIdx.x;
  int e = (int)(gid >> 5);
  int ch = (int)(gid & 31);
  if (e >= E) return;
  int is64 = *flag;
  int src = load_idx(eiv, is64, e);
  int dst = load_idx(eiv, is64, (long long)E + e);
  float4 v = *(const float4*)(x + (size_t)src * F + ch * 4);
  float* a = agg + (size_t)dst * H + ch * 4;
  atomicAdd(a + 0, v.x);
  atomicAdd(a + 1, v.y);
  atomicAdd(a + 2, v.z);
  atomicAdd(a + 3, v.w);
  if (ch == 0) atomicAdd(deg + dst, 1.0f);
}

__global__ __launch_bounds__(256) void divide_deg(float* __restrict__ out,
                                                  const float* __restrict__ deg,
                                                  long long n4) {
  long long i = (long long)blockIdx.x * blockDim.x + threadIdx.x;
  if (i >= n4) return;
  int node = (int)(i >> 5);
  float s = 1.0f / fmaxf(deg[node], 1.0f);
  float4 v = ((float4*)out)[i];
  v.x *= s; v.y *= s; v.z *= s; v.w *= s;
  ((float4*)out)[i] = v;
}

__global__ __launch_bounds__(256) void fused_gemm(
    const float* __restrict__ x, const float* __restrict__ Wl,
    const float* __restrict__ bl, const float* __restrict__ Wr,
    float* __restrict__ out, float* __restrict__ colsum, float* __restrict__ colsq) {
  __shared__ float As[16][256];
  __shared__ float rp[4][8];
  __shared__ float rscale[16];
  __shared__ float cs[128], cs2[128];

  const int t = threadIdx.x;
  const int i0 = blockIdx.x * 16;

  #pragma unroll
  for (int it = 0; it < 2; ++it) {
    int idx = (it * 256 + t) * 4;
    int r = idx >> 7, c = idx & 127;
    float4 va = *(const float4*)(out + (size_t)(i0 + r) * H + c);
    As[r][c + 0] = va.x; As[r][c + 1] = va.y;
    As[r][c + 2] = va.z; As[r][c + 3] = va.w;
    float4 vx = *(const float4*)(x + (size_t)(i0 + r) * F + c);
    As[r][128 + c + 0] = vx.x; As[r][128 + c + 1] = vx.y;
    As[r][128 + c + 2] = vx.z; As[r][128 + c + 3] = vx.w;
  }
  __syncthreads();

  const int c = t & 127;
  const int half = t >> 7;
  float acc[8];
  #pragma unroll
  for (int r = 0; r < 8; ++r) acc[r] = 0.0f;

  #pragma unroll 4
  for (int k = 0; k < 128; ++k) {
    float w = Wl[k * H + c];
    #pragma unroll
    for (int r = 0; r < 8; ++r) acc[r] = fmaf(As[half * 8 + r][k], w, acc[r]);
  }
  #pragma unroll 4
  for (int k = 0; k < 128; ++k) {
    float w = Wr[k * H + c];
    #pragma unroll
    for (int r = 0; r < 8; ++r) acc[r] = fmaf(As[half * 8 + r][128 + k], w, acc[r]);
  }
  const float bias = bl[c];
  #pragma unroll
  for (int r = 0; r < 8; ++r) acc[r] += bias;

  float sq[8];
  #pragma unroll
  for (int r = 0; r < 8; ++r) sq[r] = acc[r] * acc[r];
  #pragma unroll
  for (int off = 32; off > 0; off >>= 1) {
    #pragma unroll
    for (int r = 0; r < 8; ++r) sq[r] += __shfl_down(sq[r], off, 64);
  }
  const int wv = t >> 6;
  if ((t & 63) == 0) {
    #pragma unroll
    for (int r = 0; r < 8; ++r) rp[wv][r] = sq[r];
  }
  __syncthreads();
  if (t < 16) {
    int base = (t >> 3) * 2, rr = t & 7;
    float s = rp[base][rr] + rp[base + 1][rr];
    rscale[t] = 1.0f / fmaxf(sqrtf(s), 1e-12f);
  }
  __syncthreads();

  float csum = 0.0f, csq = 0.0f;
  #pragma unroll
  for (int r = 0; r < 8; ++r) {
    float v = fmaxf(acc[r] * rscale[half * 8 + r], 0.0f);
    out[(size_t)(i0 + half * 8 + r) * H + c] = v;
    csum += v;
    csq += v * v;
  }
  if (half == 1) { cs[c] = csum; cs2[c] = csq; }
  __syncthreads();
  if (half == 0) {
    atomicAdd(&colsum[c], csum + cs[c]);
    atomicAdd(&colsq[c], csq + cs2[c]);
  }
}

__global__ void bn_stats(const float* __restrict__ colsum, const float* __restrict__ colsq,
                         const float* __restrict__ gamma, const float* __restrict__ beta,
                         float* __restrict__ scale, float* __restrict__ shift, int n) {
  int c = threadIdx.x;
  if (c < H) {
    float inv_n = 1.0f / (float)n;
    float mean = colsum[c] * inv_n;
    float var = colsq[c] * inv_n - mean * mean;  // biased (torch BN)
    float istd = rsqrtf(var + 1e-5f);
    float sc = gamma[c] * istd;
    scale[c] = sc;
    shift[c] = beta[c] - mean * sc;
  }
}

__global__ __launch_bounds__(256) void bn_apply(
    float* __restrict__ out, const float* __restrict__ scale,
    const float* __restrict__ shift, long long n4) {
  long long i = (long long)blockIdx.x * blockDim.x + threadIdx.x;
  if (i >= n4) return;
  float4 v = ((float4*)out)[i];
  int c = (int)((i * 4) & (H - 1));
  v.x = fmaf(v.x, scale[c + 0], shift[c + 0]);
  v.y = fmaf(v.y, scale[c + 1], shift[c + 1]);
  v.z = fmaf(v.z, scale[c + 2], shift[c + 2]);
  v.w = fmaf(v.w, scale[c + 3], shift[c + 3]);
  ((float4*)out)[i] = v;
}

extern "C" void kernel_launch(void* const* d_in, const int* in_sizes, int n_in,
                              void* d_out, int out_size, void* d_ws, size_t ws_size,
                              hipStream_t stream) {
  const float* x     = (const float*)d_in[0];
  const void*  ei    = d_in[1];
  const float* Wl    = (const float*)d_in[2];
  const float* bl    = (const float*)d_in[3];
  const float* Wr    = (const float*)d_in[4];
  const float* gamma = (const float*)d_in[5];
  const float* beta  = (const float*)d_in[6];
  float* out = (float*)d_out;

  const int n = in_sizes[0] / F;   // 100000
  const int E = in_sizes[1] / 2;   // 1600000
  const int nb = (n + 255) / 256;

  char* ws = (char*)d_ws;
  int* flag = (int*)ws;

  unsigned short* Wcat = (unsigned short*)(ws + 256);
  int*   degi     = (int*)(ws + 256 + 4 * 128 * 128 * 2);
  int*   offsets  = degi + n;
  int*   cursor   = offsets + n + 1;
  int*   blocksum = cursor + n;
  int*   blockoff = blocksum + nb;
  float* colsum   = (float*)(blockoff + nb);
  float* colsq    = colsum + H;
  float* scale    = colsq + H;
  float* shift    = scale + H;
  int*   csr_src  = (int*)(shift + H);
  size_t need_mid = (size_t)((char*)(csr_src + E) - ws);
  size_t yoff = (need_mid + 255) & ~(size_t)255;
  unsigned short* Yws = (unsigned short*)(ws + yoff);
  size_t need_full = yoff + (size_t)n * H * 2;

  const int eb = (E + 255) / 256;
  const int gb = (n + 63) / 64;   // 64-row GEMM blocks
  detect_dtype<<<1, 64, 0, stream>>>((const unsigned*)ei, flag);

  if (ws_size >= need_full) {
    hipMemsetAsync(degi, 0, (size_t)n * 4, stream);
    hipMemsetAsync(colsum, 0, 2 * H * 4, stream);

    prep_w<<<32, 256, 0, stream>>>(Wl, Wr, Wcat);
    ymat<<<gb, 256, 0, stream>>>(x, Wcat, Yws, n);

    deg_count<<<eb, 256, 0, stream>>>(ei, flag, degi, E);
    scan1<<<nb, 256, 0, stream>>>(degi, offsets, blocksum, n);
    scan2<<<1, 512, 0, stream>>>(blocksum, blockoff, nb);
    scan3<<<nb, 256, 0, stream>>>(offsets, blockoff, cursor, n, E);
    bucket_fill<<<eb, 256, 0, stream>>>(ei, flag, cursor, csr_src, E);

    long long gthreads = (long long)((n + 1) / 2) * 64;
    gather_bf16<<<(int)((gthreads + 255) / 256), 256, 0, stream>>>(
        Yws, offsets, csr_src, out, n);

    final_gemm<<<gb, 256, 0, stream>>>(x, Wcat, bl, out, colsum, colsq, n);
  } else if (ws_size >= need_mid) {
    hipMemsetAsync(degi, 0, (size_t)n * 4, stream);
    hipMemsetAsync(colsum, 0, 2 * H * 4, stream);

    prep_w<<<32, 256, 0, stream>>>(Wl, Wr, Wcat);

    deg_count<<<eb, 256, 0, stream>>>(ei, flag, degi, E);
    scan1<<<nb, 256, 0, stream>>>(degi, offsets, blocksum, n);
    scan2<<<1, 512, 0, stream>>>(blocksum, blockoff, nb);
    scan3<<<nb, 256, 0, stream>>>(offsets, blockoff, cursor, n, E);
    bucket_fill<<<eb, 256, 0, stream>>>(ei, flag, cursor, csr_src, E);

    long long gthreads = (long long)n * 64;
    gather_mean<<<(int)((gthreads + 255) / 256), 256, 0, stream>>>(
        x, offsets, csr_src, out, n);

    mfma_gemm<<<gb, 256, 0, stream>>>(x, Wcat, bl, out, colsum, colsq, n);
  } else {
    float* deg = (float*)(ws + 256);
    colsum = deg + n; colsq = colsum + H; scale = colsq + H; shift = scale + H;
    hipMemsetAsync(d_out, 0, (size_t)out_size * sizeof(float), stream);
    hipMemsetAsync(deg, 0, (size_t)n * 4 + 4 * H * 4, stream);
    long long sthreads = (long long)E * 32;
    scatter_mean<<<(int)((sthreads + 255) / 256), 256, 0, stream>>>(x, ei, flag, out, deg, E);
    long long n4f = (long long)n * H / 4;
    divide_deg<<<(int)((n4f + 255) / 256), 256, 0, stream>>>(out, deg, n4f);
    fused_gemm<<<n / 16, 256, 0, stream>>>(x, Wl, bl, Wr, out, colsum, colsq);
  }

  bn_stats<<<1, 128, 0, stream>>>(colsum, colsq, gamma, beta, scale, shift, n);
  long long n4 = (long long)n * H / 4;
  bn_apply<<<(int)((n4 + 255) / 256), 256, 0, stream>>>(out, scale, shift, n4);
}